// Round 1
// baseline (169.317 us; speedup 1.0000x reference)
//
#include <hip/hip_runtime.h>
#include <math.h>

// Sizes
#define BATCH 128
#define EPTS  512
#define EPSV  1e-5f

// ---------------------------------------------------------------------------
// Kernel A: wireframe (scatter-max) + conv1 (1->4, 3x3 SAME, 28x28) + bn1 stats
// grid = 128 (one block per batch item), block = 256
// ---------------------------------------------------------------------------
__global__ __launch_bounds__(256) void k_wire_conv1(
    const float* __restrict__ x_in,   // (128,512,3)
    const float* __restrict__ w1,     // (4,1,3,3)
    const float* __restrict__ b1,     // (4,)
    float* __restrict__ y1,           // (128,4,28,28)
    double* __restrict__ acc1)        // [0..4) sum, [4..8) sumsq
{
    __shared__ float sI[784];          // 28x28 wireframe image (as float bits)
    __shared__ float sw[36];
    __shared__ float sb[4];
    __shared__ float sS[4], sQ[4];

    const int tid = threadIdx.x;
    const int b  = blockIdx.x;

    for (int i = tid; i < 784; i += 256) sI[i] = 0.0f;
    if (tid < 36) sw[tid] = w1[tid];
    if (tid < 4) { sb[tid] = b1[tid]; sS[tid] = 0.0f; sQ[tid] = 0.0f; }
    __syncthreads();

    // scatter-max: each point touches at most a 2x2 patch
    for (int e = tid; e < EPTS; e += 256) {
        const float* xe = x_in + ((size_t)b * EPTS + e) * 3;
        float p  = xe[0];
        float tx = xe[1] * 28.0f;
        float ty = xe[2] * 28.0f;
        int x0 = (int)floorf(tx); float fx = tx - (float)x0;
        int y0 = (int)floorf(ty); float fy = ty - (float)y0;
        float kx[2] = {1.0f - fx, fx};
        float ky[2] = {1.0f - fy, fy};
        #pragma unroll
        for (int dx = 0; dx < 2; ++dx) {
            int gx = x0 + dx;
            if (gx < 0 || gx > 27) continue;
            #pragma unroll
            for (int dy = 0; dy < 2; ++dy) {
                int gy = y0 + dy;
                if (gy < 0 || gy > 27) continue;
                float v = p * (kx[dx] * ky[dy]);   // >= 0
                atomicMax((int*)&sI[gx * 28 + gy], __float_as_int(v));
            }
        }
    }
    __syncthreads();

    // conv1 + per-channel sum / sumsq
    for (int idx = tid; idx < 4 * 784; idx += 256) {
        int o = idx / 784, pix = idx % 784;
        int i = pix / 28, j = pix % 28;
        float s = sb[o];
        #pragma unroll
        for (int a = 0; a < 3; ++a) {
            int ii = i + a - 1;
            if (ii < 0 || ii > 27) continue;
            #pragma unroll
            for (int c = 0; c < 3; ++c) {
                int jj = j + c - 1;
                if (jj < 0 || jj > 27) continue;
                s += sw[o * 9 + a * 3 + c] * sI[ii * 28 + jj];
            }
        }
        y1[((size_t)b * 4 + o) * 784 + pix] = s;
        atomicAdd(&sS[o], s);
        atomicAdd(&sQ[o], s * s);
    }
    __syncthreads();
    if (tid < 4) {
        atomicAdd(&acc1[tid],     (double)sS[tid]);
        atomicAdd(&acc1[4 + tid], (double)sQ[tid]);
    }
}

// ---------------------------------------------------------------------------
// Kernel B: bn1+relu+pool (28->14) + conv2 (4->8) + bn2 stats
// ---------------------------------------------------------------------------
__global__ __launch_bounds__(256) void k_bnpool1_conv2(
    const float* __restrict__ y1,     // (128,4,28,28)
    const double* __restrict__ acc1,
    const float* __restrict__ g1, const float* __restrict__ be1,
    const float* __restrict__ w2,     // (8,4,3,3) = 288
    const float* __restrict__ b2,     // (8,)
    float* __restrict__ y2,           // (128,8,14,14)
    double* __restrict__ acc2)        // [0..8) sum, [8..16) sumsq
{
    __shared__ float sx[4 * 196];     // pooled input 4x14x14
    __shared__ float sw[288];
    __shared__ float sb2[8];
    __shared__ float sc[4], sf[4];
    __shared__ float sS[8], sQ[8];

    const int tid = threadIdx.x;
    const int b  = blockIdx.x;

    for (int i = tid; i < 288; i += 256) sw[i] = w2[i];
    if (tid < 8) { sb2[tid] = b2[tid]; sS[tid] = 0.0f; sQ[tid] = 0.0f; }
    if (tid < 4) {
        const double n = 128.0 * 784.0;
        double m = acc1[tid] / n;
        double v = acc1[4 + tid] / n - m * m;
        float scale = g1[tid] * rsqrtf((float)v + EPSV);
        sc[tid] = scale;
        sf[tid] = be1[tid] - (float)m * scale;
    }
    __syncthreads();

    // bn + relu + 2x2 maxpool -> LDS
    for (int idx = tid; idx < 4 * 196; idx += 256) {
        int c = idx / 196, pix = idx % 196;
        int r = pix / 14, col = pix % 14;
        const float* yb = y1 + ((size_t)b * 4 + c) * 784;
        float scale = sc[c], shift = sf[c];
        float m0 = fmaxf(yb[(2*r    )*28 + 2*col], yb[(2*r    )*28 + 2*col + 1]);
        float m1 = fmaxf(yb[(2*r + 1)*28 + 2*col], yb[(2*r + 1)*28 + 2*col + 1]);
        float m = fmaxf(m0, m1) * scale + shift;   // scale>0 always (g=1 at init... but be safe)
        // NOTE: scale could be negative in general (gamma<0). Do bn first, then max.
        float v00 = yb[(2*r    )*28 + 2*col    ] * scale + shift;
        float v01 = yb[(2*r    )*28 + 2*col + 1] * scale + shift;
        float v10 = yb[(2*r + 1)*28 + 2*col    ] * scale + shift;
        float v11 = yb[(2*r + 1)*28 + 2*col + 1] * scale + shift;
        m = fmaxf(fmaxf(v00, v01), fmaxf(v10, v11));
        sx[c * 196 + pix] = fmaxf(m, 0.0f);
    }
    __syncthreads();

    // conv2 + stats
    for (int idx = tid; idx < 8 * 196; idx += 256) {
        int o = idx / 196, pix = idx % 196;
        int i = pix / 14, j = pix % 14;
        float s = sb2[o];
        #pragma unroll
        for (int c = 0; c < 4; ++c) {
            #pragma unroll
            for (int a = 0; a < 3; ++a) {
                int ii = i + a - 1;
                if (ii < 0 || ii > 13) continue;
                #pragma unroll
                for (int d = 0; d < 3; ++d) {
                    int jj = j + d - 1;
                    if (jj < 0 || jj > 13) continue;
                    s += sw[((o * 4 + c) * 3 + a) * 3 + d] * sx[c * 196 + ii * 14 + jj];
                }
            }
        }
        y2[((size_t)b * 8 + o) * 196 + pix] = s;
        atomicAdd(&sS[o], s);
        atomicAdd(&sQ[o], s * s);
    }
    __syncthreads();
    if (tid < 8) {
        atomicAdd(&acc2[tid],     (double)sS[tid]);
        atomicAdd(&acc2[8 + tid], (double)sQ[tid]);
    }
}

// ---------------------------------------------------------------------------
// Kernel C: bn2+relu+pool (14->7) + conv3 (8->16) + bn3 stats
// ---------------------------------------------------------------------------
__global__ __launch_bounds__(256) void k_bnpool2_conv3(
    const float* __restrict__ y2,     // (128,8,14,14)
    const double* __restrict__ acc2,
    const float* __restrict__ g2, const float* __restrict__ be2,
    const float* __restrict__ w3,     // (16,8,3,3) = 1152
    const float* __restrict__ b3,     // (16,)
    float* __restrict__ y3,           // (128,16,7,7)
    double* __restrict__ acc3)        // [0..16) sum, [16..32) sumsq
{
    __shared__ float sx[8 * 49];
    __shared__ float sw[1152];
    __shared__ float sb3[16];
    __shared__ float sc[8], sf[8];
    __shared__ float sS[16], sQ[16];

    const int tid = threadIdx.x;
    const int b  = blockIdx.x;

    for (int i = tid; i < 1152; i += 256) sw[i] = w3[i];
    if (tid < 16) { sb3[tid] = b3[tid]; sS[tid] = 0.0f; sQ[tid] = 0.0f; }
    if (tid < 8) {
        const double n = 128.0 * 196.0;
        double m = acc2[tid] / n;
        double v = acc2[8 + tid] / n - m * m;
        float scale = g2[tid] * rsqrtf((float)v + EPSV);
        sc[tid] = scale;
        sf[tid] = be2[tid] - (float)m * scale;
    }
    __syncthreads();

    for (int idx = tid; idx < 8 * 49; idx += 256) {
        int c = idx / 49, pix = idx % 49;
        int r = pix / 7, col = pix % 7;
        const float* yb = y2 + ((size_t)b * 8 + c) * 196;
        float scale = sc[c], shift = sf[c];
        float v00 = yb[(2*r    )*14 + 2*col    ] * scale + shift;
        float v01 = yb[(2*r    )*14 + 2*col + 1] * scale + shift;
        float v10 = yb[(2*r + 1)*14 + 2*col    ] * scale + shift;
        float v11 = yb[(2*r + 1)*14 + 2*col + 1] * scale + shift;
        float m = fmaxf(fmaxf(v00, v01), fmaxf(v10, v11));
        sx[c * 49 + pix] = fmaxf(m, 0.0f);
    }
    __syncthreads();

    for (int idx = tid; idx < 16 * 49; idx += 256) {
        int o = idx / 49, pix = idx % 49;
        int i = pix / 7, j = pix % 7;
        float s = sb3[o];
        #pragma unroll
        for (int c = 0; c < 8; ++c) {
            #pragma unroll
            for (int a = 0; a < 3; ++a) {
                int ii = i + a - 1;
                if (ii < 0 || ii > 6) continue;
                #pragma unroll
                for (int d = 0; d < 3; ++d) {
                    int jj = j + d - 1;
                    if (jj < 0 || jj > 6) continue;
                    s += sw[((o * 8 + c) * 3 + a) * 3 + d] * sx[c * 49 + ii * 7 + jj];
                }
            }
        }
        y3[((size_t)b * 16 + o) * 49 + pix] = s;
        atomicAdd(&sS[o], s);
        atomicAdd(&sQ[o], s * s);
    }
    __syncthreads();
    if (tid < 16) {
        atomicAdd(&acc3[tid],      (double)sS[tid]);
        atomicAdd(&acc3[16 + tid], (double)sQ[tid]);
    }
}

// ---------------------------------------------------------------------------
// Kernel D: bn3+relu + fc1(784->128)+relu + fc2(128->1) + mean over batch
// ---------------------------------------------------------------------------
__global__ __launch_bounds__(256) void k_bn3_fc(
    const float* __restrict__ y3,     // (128,16,7,7) = (128,784)
    const double* __restrict__ acc3,
    const float* __restrict__ g3, const float* __restrict__ be3,
    const float* __restrict__ fc1w,   // (128,784)
    const float* __restrict__ fc1b,   // (128,)
    const float* __restrict__ fc2w,   // (1,128)
    const float* __restrict__ fc2b,   // (1,)
    float* __restrict__ out)          // (1,)
{
    __shared__ __align__(16) float sx[784];
    __shared__ float sh[128];
    __shared__ float sc[16], sf[16];
    __shared__ float red[128];

    const int tid = threadIdx.x;
    const int b  = blockIdx.x;

    if (tid < 16) {
        const double n = 128.0 * 49.0;
        double m = acc3[tid] / n;
        double v = acc3[16 + tid] / n - m * m;
        float scale = g3[tid] * rsqrtf((float)v + EPSV);
        sc[tid] = scale;
        sf[tid] = be3[tid] - (float)m * scale;
    }
    __syncthreads();

    for (int idx = tid; idx < 784; idx += 256) {
        int c = idx / 49;
        float v = y3[(size_t)b * 784 + idx] * sc[c] + sf[c];
        sx[idx] = fmaxf(v, 0.0f);
    }
    __syncthreads();

    // fc1: two threads per output row j, 392 elements each
    const int j = tid >> 1, half = tid & 1;
    const float4* wr4 = (const float4*)(fc1w + (size_t)j * 784 + half * 392);
    const float4* xr4 = (const float4*)(sx) + half * 98;
    float s = 0.0f;
    #pragma unroll 4
    for (int k = 0; k < 98; ++k) {
        float4 w4 = wr4[k];
        float4 x4 = xr4[k];
        s += w4.x * x4.x + w4.y * x4.y + w4.z * x4.z + w4.w * x4.w;
    }
    s += __shfl_xor(s, 1);
    if (half == 0) sh[j] = fmaxf(s + fc1b[j], 0.0f);
    __syncthreads();

    // fc2 + block reduce
    if (tid < 128) red[tid] = sh[tid] * fc2w[tid];
    __syncthreads();
    if (tid < 64) red[tid] += red[tid + 64];
    __syncthreads();
    if (tid < 64) {
        float v = red[tid];
        for (int off = 32; off; off >>= 1) v += __shfl_down(v, off);
        if (tid == 0) atomicAdd(out, (v + fc2b[0]) * (1.0f / 128.0f));
    }
}

// ---------------------------------------------------------------------------
extern "C" void kernel_launch(void* const* d_in, const int* in_sizes, int n_in,
                              void* d_out, int out_size, void* d_ws, size_t ws_size,
                              hipStream_t stream) {
    const float* x_in  = (const float*)d_in[0];
    const float* w1    = (const float*)d_in[1];
    const float* b1    = (const float*)d_in[2];
    const float* g1    = (const float*)d_in[3];
    const float* be1   = (const float*)d_in[4];
    const float* w2    = (const float*)d_in[5];
    const float* b2    = (const float*)d_in[6];
    const float* g2    = (const float*)d_in[7];
    const float* be2   = (const float*)d_in[8];
    const float* w3    = (const float*)d_in[9];
    const float* b3    = (const float*)d_in[10];
    const float* g3    = (const float*)d_in[11];
    const float* be3   = (const float*)d_in[12];
    const float* fc1w  = (const float*)d_in[13];
    const float* fc1b  = (const float*)d_in[14];
    const float* fc2w  = (const float*)d_in[15];
    const float* fc2b  = (const float*)d_in[16];

    char* ws = (char*)d_ws;
    double* acc  = (double*)ws;          // 56 doubles total
    double* acc1 = acc;                  // 8
    double* acc2 = acc + 8;              // 16
    double* acc3 = acc + 24;             // 32
    float* y1 = (float*)(ws + 448);                  // 128*4*784
    float* y2 = y1 + (size_t)128 * 4 * 784;          // 128*8*196
    float* y3 = y2 + (size_t)128 * 8 * 196;          // 128*16*49

    hipMemsetAsync(acc, 0, 56 * sizeof(double), stream);
    hipMemsetAsync(d_out, 0, sizeof(float), stream);

    k_wire_conv1   <<<128, 256, 0, stream>>>(x_in, w1, b1, y1, acc1);
    k_bnpool1_conv2<<<128, 256, 0, stream>>>(y1, acc1, g1, be1, w2, b2, y2, acc2);
    k_bnpool2_conv3<<<128, 256, 0, stream>>>(y2, acc2, g2, be2, w3, b3, y3, acc3);
    k_bn3_fc       <<<128, 256, 0, stream>>>(y3, acc3, g3, be3, fc1w, fc1b, fc2w, fc2b,
                                             (float*)d_out);
}

// Round 2
// 168.568 us; speedup vs baseline: 1.0044x; 1.0044x over previous
//
#include <hip/hip_runtime.h>
#include <math.h>

#define EPSV 1e-5f

// ws layout (floats):
//   pp1 @ 0       : 128*8   per-block (sum[4], sumsq[4]) of conv1 out
//   pp2 @ 1024    : 128*16
//   pp3 @ 3072    : 128*32
//   pf  @ 7168    : 128     per-block fc2 dot (no bias)
//   y1  @ 7296    : 128*4*784
//   y2  @ 408704  : 128*8*196
//   y3  @ 609408  : 128*16*49

// ---------------------------------------------------------------------------
// Kernel A: wireframe scatter-max + conv1 (1->4) + per-block bn1 partials
// ---------------------------------------------------------------------------
__global__ __launch_bounds__(256) void k_wire_conv1(
    const float* __restrict__ x_in,   // (128,512,3)
    const float* __restrict__ w1,     // (4,1,3,3)
    const float* __restrict__ b1,     // (4,)
    float* __restrict__ y1,           // (128,4,28,28)
    float* __restrict__ pp1)          // (128,8)
{
    __shared__ float sI[784];
    __shared__ float sw[36];

    const int tid  = threadIdx.x;
    const int lane = tid & 63;
    const int o    = tid >> 6;        // wave id == out channel (4 waves)
    const int b    = blockIdx.x;

    for (int i = tid; i < 784; i += 256) sI[i] = 0.0f;
    if (tid < 36) sw[tid] = w1[tid];
    __syncthreads();

    // scatter-max: each point touches at most a 2x2 patch; products >= 0
    for (int e = tid; e < 512; e += 256) {
        const float* xe = x_in + ((size_t)b * 512 + e) * 3;
        float p  = xe[0];
        float tx = xe[1] * 28.0f;
        float ty = xe[2] * 28.0f;
        int x0 = (int)floorf(tx); float fx = tx - (float)x0;
        int y0 = (int)floorf(ty); float fy = ty - (float)y0;
        float kx[2] = {1.0f - fx, fx};
        float ky[2] = {1.0f - fy, fy};
        #pragma unroll
        for (int dx = 0; dx < 2; ++dx) {
            int gx = x0 + dx;
            if (gx < 0 || gx > 27) continue;
            #pragma unroll
            for (int dy = 0; dy < 2; ++dy) {
                int gy = y0 + dy;
                if (gy < 0 || gy > 27) continue;
                float v = p * (kx[dx] * ky[dy]);
                atomicMax((int*)&sI[gx * 28 + gy], __float_as_int(v));
            }
        }
    }
    __syncthreads();

    // conv1: wave o computes channel o; per-lane stat accumulation
    const float bias = b1[o];
    float ls = 0.0f, lq = 0.0f;
    float* yb = y1 + ((size_t)b * 4 + o) * 784;
    for (int p = lane; p < 784; p += 64) {
        int i = p / 28, j = p % 28;
        float s = bias;
        #pragma unroll
        for (int a = 0; a < 3; ++a) {
            int ii = i + a - 1;
            if (ii < 0 || ii > 27) continue;
            #pragma unroll
            for (int c = 0; c < 3; ++c) {
                int jj = j + c - 1;
                if (jj < 0 || jj > 27) continue;
                s += sw[o * 9 + a * 3 + c] * sI[ii * 28 + jj];
            }
        }
        yb[p] = s;
        ls += s; lq += s * s;
    }
    #pragma unroll
    for (int off = 32; off; off >>= 1) {
        ls += __shfl_down(ls, off);
        lq += __shfl_down(lq, off);
    }
    if (lane == 0) { pp1[b * 8 + o] = ls; pp1[b * 8 + 4 + o] = lq; }
}

// ---------------------------------------------------------------------------
// Kernel B: reduce bn1 stats + bn1/relu/pool (28->14) + conv2 (4->8) + partials
// ---------------------------------------------------------------------------
__global__ __launch_bounds__(256) void k_bnpool1_conv2(
    const float* __restrict__ y1,
    const float* __restrict__ pp1,    // (128,8)
    const float* __restrict__ g1, const float* __restrict__ be1,
    const float* __restrict__ w2,     // 288
    const float* __restrict__ b2,     // 8
    float* __restrict__ y2,           // (128,8,14,14)
    float* __restrict__ pp2)          // (128,16)
{
    __shared__ float sx[4 * 196];
    __shared__ float sw[288];
    __shared__ float sc[4], sf[4];
    __shared__ double sred[8];

    const int tid = threadIdx.x;
    const int b   = blockIdx.x;

    for (int i = tid; i < 288; i += 256) sw[i] = w2[i];

    // cross-block stat reduction: 8 stats x 8 lanes each (wave 0)
    if (tid < 64) {
        int c = tid >> 3, k = tid & 7;
        double t = 0.0;
        for (int i = k; i < 128; i += 8) t += (double)pp1[i * 8 + c];
        t += __shfl_down(t, 4); t += __shfl_down(t, 2); t += __shfl_down(t, 1);
        if (k == 0) sred[c] = t;
    }
    __syncthreads();
    if (tid < 4) {
        const double n = 128.0 * 784.0;
        double m = sred[tid] / n;
        double v = sred[4 + tid] / n - m * m;
        float scale = g1[tid] * rsqrtf((float)v + EPSV);
        sc[tid] = scale;
        sf[tid] = be1[tid] - (float)m * scale;
    }
    __syncthreads();

    // bn + relu + 2x2 maxpool -> LDS
    for (int idx = tid; idx < 4 * 196; idx += 256) {
        int c = idx / 196, pix = idx % 196;
        int r = pix / 14, col = pix % 14;
        const float* yb = y1 + ((size_t)b * 4 + c) * 784;
        float scale = sc[c], shift = sf[c];
        float v00 = yb[(2*r    )*28 + 2*col    ] * scale + shift;
        float v01 = yb[(2*r    )*28 + 2*col + 1] * scale + shift;
        float v10 = yb[(2*r + 1)*28 + 2*col    ] * scale + shift;
        float v11 = yb[(2*r + 1)*28 + 2*col + 1] * scale + shift;
        float m = fmaxf(fmaxf(v00, v01), fmaxf(v10, v11));
        sx[c * 196 + pix] = fmaxf(m, 0.0f);
    }
    __syncthreads();

    // conv2: 8 groups of 32 lanes; group g computes channel g
    const int o = tid >> 5, l32 = tid & 31;
    const float bias = b2[o];
    float ls = 0.0f, lq = 0.0f;
    float* yo = y2 + ((size_t)b * 8 + o) * 196;
    for (int p = l32; p < 196; p += 32) {
        int i = p / 14, j = p % 14;
        float s = bias;
        #pragma unroll
        for (int c = 0; c < 4; ++c) {
            #pragma unroll
            for (int a = 0; a < 3; ++a) {
                int ii = i + a - 1;
                if (ii < 0 || ii > 13) continue;
                #pragma unroll
                for (int d = 0; d < 3; ++d) {
                    int jj = j + d - 1;
                    if (jj < 0 || jj > 13) continue;
                    s += sw[((o * 4 + c) * 3 + a) * 3 + d] * sx[c * 196 + ii * 14 + jj];
                }
            }
        }
        yo[p] = s;
        ls += s; lq += s * s;
    }
    #pragma unroll
    for (int off = 16; off; off >>= 1) {      // xor stays within 32-lane half
        ls += __shfl_xor(ls, off);
        lq += __shfl_xor(lq, off);
    }
    if (l32 == 0) { pp2[b * 16 + o] = ls; pp2[b * 16 + 8 + o] = lq; }
}

// ---------------------------------------------------------------------------
// Kernel C: reduce bn2 stats + bn2/relu/pool (14->7) + conv3 (8->16) + partials
// ---------------------------------------------------------------------------
__global__ __launch_bounds__(256) void k_bnpool2_conv3(
    const float* __restrict__ y2,
    const float* __restrict__ pp2,    // (128,16)
    const float* __restrict__ g2, const float* __restrict__ be2,
    const float* __restrict__ w3,     // 1152
    const float* __restrict__ b3,     // 16
    float* __restrict__ y3,           // (128,16,7,7)
    float* __restrict__ pp3)          // (128,32)
{
    __shared__ float sx[8 * 49];
    __shared__ float sw[1152];
    __shared__ float sc[8], sf[8];
    __shared__ double sred[16];

    const int tid = threadIdx.x;
    const int b   = blockIdx.x;

    for (int i = tid; i < 1152; i += 256) sw[i] = w3[i];

    if (tid < 64) {
        int c = tid >> 2, k = tid & 3;
        double t = 0.0;
        for (int i = k; i < 128; i += 4) t += (double)pp2[i * 16 + c];
        t += __shfl_down(t, 2); t += __shfl_down(t, 1);
        if (k == 0) sred[c] = t;
    }
    __syncthreads();
    if (tid < 8) {
        const double n = 128.0 * 196.0;
        double m = sred[tid] / n;
        double v = sred[8 + tid] / n - m * m;
        float scale = g2[tid] * rsqrtf((float)v + EPSV);
        sc[tid] = scale;
        sf[tid] = be2[tid] - (float)m * scale;
    }
    __syncthreads();

    for (int idx = tid; idx < 8 * 49; idx += 256) {
        int c = idx / 49, pix = idx % 49;
        int r = pix / 7, col = pix % 7;
        const float* yb = y2 + ((size_t)b * 8 + c) * 196;
        float scale = sc[c], shift = sf[c];
        float v00 = yb[(2*r    )*14 + 2*col    ] * scale + shift;
        float v01 = yb[(2*r    )*14 + 2*col + 1] * scale + shift;
        float v10 = yb[(2*r + 1)*14 + 2*col    ] * scale + shift;
        float v11 = yb[(2*r + 1)*14 + 2*col + 1] * scale + shift;
        float m = fmaxf(fmaxf(v00, v01), fmaxf(v10, v11));
        sx[c * 49 + pix] = fmaxf(m, 0.0f);
    }
    __syncthreads();

    // conv3: 16 groups of 16 lanes; group g computes channel g
    const int o = tid >> 4, l16 = tid & 15;
    const float bias = b3[o];
    float ls = 0.0f, lq = 0.0f;
    float* yo = y3 + ((size_t)b * 16 + o) * 49;
    for (int p = l16; p < 49; p += 16) {
        int i = p / 7, j = p % 7;
        float s = bias;
        #pragma unroll
        for (int c = 0; c < 8; ++c) {
            #pragma unroll
            for (int a = 0; a < 3; ++a) {
                int ii = i + a - 1;
                if (ii < 0 || ii > 6) continue;
                #pragma unroll
                for (int d = 0; d < 3; ++d) {
                    int jj = j + d - 1;
                    if (jj < 0 || jj > 6) continue;
                    s += sw[((o * 8 + c) * 3 + a) * 3 + d] * sx[c * 49 + ii * 7 + jj];
                }
            }
        }
        yo[p] = s;
        ls += s; lq += s * s;
    }
    #pragma unroll
    for (int off = 8; off; off >>= 1) {       // xor stays within 16-lane group
        ls += __shfl_xor(ls, off);
        lq += __shfl_xor(lq, off);
    }
    if (l16 == 0) { pp3[b * 32 + o] = ls; pp3[b * 32 + 16 + o] = lq; }
}

// ---------------------------------------------------------------------------
// Kernel D: reduce bn3 stats + bn3/relu + fc1+relu + fc2 dot -> per-block pf
// ---------------------------------------------------------------------------
__global__ __launch_bounds__(256) void k_bn3_fc(
    const float* __restrict__ y3,     // (128,784)
    const float* __restrict__ pp3,    // (128,32)
    const float* __restrict__ g3, const float* __restrict__ be3,
    const float* __restrict__ fc1w,   // (128,784)
    const float* __restrict__ fc1b,   // (128,)
    const float* __restrict__ fc2w,   // (128,)
    float* __restrict__ pf)           // (128,)
{
    __shared__ __align__(16) float sx[784];
    __shared__ float sh[128];
    __shared__ float sc[16], sf[16];
    __shared__ double sred[32];
    __shared__ float red[64];

    const int tid = threadIdx.x;
    const int b   = blockIdx.x;

    if (tid < 64) {
        int c = tid >> 1, k = tid & 1;
        double t = 0.0;
        for (int i = k; i < 128; i += 2) t += (double)pp3[i * 32 + c];
        t += __shfl_down(t, 1);
        if (k == 0) sred[c] = t;
    }
    __syncthreads();
    if (tid < 16) {
        const double n = 128.0 * 49.0;
        double m = sred[tid] / n;
        double v = sred[16 + tid] / n - m * m;
        float scale = g3[tid] * rsqrtf((float)v + EPSV);
        sc[tid] = scale;
        sf[tid] = be3[tid] - (float)m * scale;
    }
    __syncthreads();

    for (int idx = tid; idx < 784; idx += 256) {
        int c = idx / 49;
        float v = y3[(size_t)b * 784 + idx] * sc[c] + sf[c];
        sx[idx] = fmaxf(v, 0.0f);
    }
    __syncthreads();

    // fc1: two threads per output row
    const int j = tid >> 1, half = tid & 1;
    const float4* wr4 = (const float4*)(fc1w + (size_t)j * 784 + half * 392);
    const float4* xr4 = (const float4*)(sx) + half * 98;
    float s = 0.0f;
    #pragma unroll 4
    for (int k = 0; k < 98; ++k) {
        float4 w4 = wr4[k];
        float4 x4 = xr4[k];
        s += w4.x * x4.x + w4.y * x4.y + w4.z * x4.z + w4.w * x4.w;
    }
    s += __shfl_xor(s, 1);
    if (half == 0) sh[j] = fmaxf(s + fc1b[j], 0.0f);
    __syncthreads();

    // fc2 dot (no bias) -> pf[b]
    if (tid < 64) {
        float v = sh[tid] * fc2w[tid] + sh[tid + 64] * fc2w[tid + 64];
        #pragma unroll
        for (int off = 32; off; off >>= 1) v += __shfl_xor(v, off);
        if (tid == 0) pf[b] = v;
    }
}

// ---------------------------------------------------------------------------
// Kernel E: final mean over batch
// ---------------------------------------------------------------------------
__global__ __launch_bounds__(64) void k_final(
    const float* __restrict__ pf,     // (128,)
    const float* __restrict__ fc2b,   // (1,)
    float* __restrict__ out)          // (1,)
{
    const int tid = threadIdx.x;
    float v = pf[tid] + pf[tid + 64];
    #pragma unroll
    for (int off = 32; off; off >>= 1) v += __shfl_xor(v, off);
    if (tid == 0) out[0] = v * (1.0f / 128.0f) + fc2b[0];
}

// ---------------------------------------------------------------------------
extern "C" void kernel_launch(void* const* d_in, const int* in_sizes, int n_in,
                              void* d_out, int out_size, void* d_ws, size_t ws_size,
                              hipStream_t stream) {
    const float* x_in  = (const float*)d_in[0];
    const float* w1    = (const float*)d_in[1];
    const float* b1    = (const float*)d_in[2];
    const float* g1    = (const float*)d_in[3];
    const float* be1   = (const float*)d_in[4];
    const float* w2    = (const float*)d_in[5];
    const float* b2    = (const float*)d_in[6];
    const float* g2    = (const float*)d_in[7];
    const float* be2   = (const float*)d_in[8];
    const float* w3    = (const float*)d_in[9];
    const float* b3    = (const float*)d_in[10];
    const float* g3    = (const float*)d_in[11];
    const float* be3   = (const float*)d_in[12];
    const float* fc1w  = (const float*)d_in[13];
    const float* fc1b  = (const float*)d_in[14];
    const float* fc2w  = (const float*)d_in[15];
    const float* fc2b  = (const float*)d_in[16];

    float* ws  = (float*)d_ws;
    float* pp1 = ws;                    // 1024
    float* pp2 = ws + 1024;             // 2048
    float* pp3 = ws + 3072;             // 4096
    float* pf  = ws + 7168;             // 128
    float* y1  = ws + 7296;             // 401408
    float* y2  = y1 + 401408;           // 200704
    float* y3  = y2 + 200704;           // 100352

    k_wire_conv1   <<<128, 256, 0, stream>>>(x_in, w1, b1, y1, pp1);
    k_bnpool1_conv2<<<128, 256, 0, stream>>>(y1, pp1, g1, be1, w2, b2, y2, pp2);
    k_bnpool2_conv3<<<128, 256, 0, stream>>>(y2, pp2, g2, be2, w3, b3, y3, pp3);
    k_bn3_fc       <<<128, 256, 0, stream>>>(y3, pp3, g3, be3, fc1w, fc1b, fc2w, pf);
    k_final        <<<1, 64, 0, stream>>>(pf, fc2b, (float*)d_out);
}